// Round 1
// baseline (2985.278 us; speedup 1.0000x reference)
//
#include <hip/hip_runtime.h>

#define B_   256
#define D_   512
#define H_   1024
#define G_   4096           // 4*H
#define BH_  (B_ * H_)      // 262144
#define KTOT 2048           // 1024 (x-path) + 1024 (h-path)

struct Level {
    int n[4];
    int p[4];
    int cnt;
};

// ---------------------------------------------------------------------------
// GEMM: g[slot] (256 x 4096) = A (256 x 2048) @ W^T  (no bias; bias in gates)
// A columns: layer0: [input(512) | bridge(512) | h_parent_l0(1024)]
//            layer1: [h_self_l0(1024) | h_parent_l1(1024)]
// W rows:    [Wih[layer] cols 0..1023 | Whh[layer] cols 1024..2047]
// Tile: 64x64 per block, 256 threads, 4x4 per thread, BK=32.
// ---------------------------------------------------------------------------
__global__ __launch_bounds__(256)
void cell_gemm(const float* __restrict__ input, const float* __restrict__ bridge,
               const float* __restrict__ Wih, const float* __restrict__ Whh,
               const float* __restrict__ h_buf, float* __restrict__ g_buf,
               int layer, Level lv)
{
    __shared__ float As[64][33];
    __shared__ float Bs[64][33];

    const int slot = blockIdx.z;
    const int node = lv.n[slot];
    const int par  = lv.p[slot];
    const int tid  = threadIdx.x;
    const int bm   = blockIdx.y * 64;   // batch rows
    const int bn   = blockIdx.x * 64;   // gate columns (of 4096)

    const int ty = tid >> 4;            // 0..15
    const int tx = tid & 15;            // 0..15

    float acc[4][4] = {};

    for (int k0 = 0; k0 < KTOT; k0 += 32) {
        // ---- resolve A source (uniform per k-tile; segments are 512-aligned)
        const float* abase; int astride;
        if (layer == 0) {
            if (k0 < 512) {
                abase = input + (size_t)(node - 1) * B_ * D_ + k0;       astride = D_;
            } else if (k0 < 1024) {
                abase = bridge + (size_t)(node - 1) * B_ * D_ + (k0 - 512); astride = D_;
            } else {
                abase = h_buf + ((size_t)par * 2 + 0) * BH_ + (k0 - 1024);  astride = H_;
            }
        } else {
            if (k0 < 1024) {
                abase = h_buf + ((size_t)node * 2 + 0) * BH_ + k0;          astride = H_;
            } else {
                abase = h_buf + ((size_t)par * 2 + 1) * BH_ + (k0 - 1024);  astride = H_;
            }
        }
        // ---- resolve W source
        const float* bbase = (k0 < 1024)
            ? (Wih + (size_t)layer * G_ * H_ + k0)
            : (Whh + (size_t)layer * G_ * H_ + (k0 - 1024));

        // ---- stage A tile (64 x 32): 512 float4 across 256 threads x 2
        #pragma unroll
        for (int r = 0; r < 2; ++r) {
            const int e   = tid + r * 256;      // 0..511
            const int row = e >> 3;
            const int kq  = (e & 7) << 2;
            const float4 v = *reinterpret_cast<const float4*>(
                abase + (size_t)(bm + row) * astride + kq);
            As[row][kq + 0] = v.x; As[row][kq + 1] = v.y;
            As[row][kq + 2] = v.z; As[row][kq + 3] = v.w;
        }
        // ---- stage W tile (64 x 32)
        #pragma unroll
        for (int r = 0; r < 2; ++r) {
            const int e   = tid + r * 256;
            const int row = e >> 3;
            const int kq  = (e & 7) << 2;
            const float4 v = *reinterpret_cast<const float4*>(
                bbase + (size_t)(bn + row) * H_ + kq);
            Bs[row][kq + 0] = v.x; Bs[row][kq + 1] = v.y;
            Bs[row][kq + 2] = v.z; Bs[row][kq + 3] = v.w;
        }
        __syncthreads();

        #pragma unroll
        for (int kk = 0; kk < 32; ++kk) {
            float a[4], b[4];
            #pragma unroll
            for (int i = 0; i < 4; ++i) a[i] = As[ty * 4 + i][kk];
            #pragma unroll
            for (int j = 0; j < 4; ++j) b[j] = Bs[tx * 4 + j][kk];
            #pragma unroll
            for (int i = 0; i < 4; ++i)
                #pragma unroll
                for (int j = 0; j < 4; ++j)
                    acc[i][j] += a[i] * b[j];
        }
        __syncthreads();
    }

    // ---- write g
    float* gp = g_buf + (size_t)slot * B_ * G_;
    #pragma unroll
    for (int i = 0; i < 4; ++i) {
        const int row = bm + ty * 4 + i;
        #pragma unroll
        for (int j = 0; j < 4; ++j) {
            gp[(size_t)row * G_ + bn + tx * 4 + j] = acc[i][j];
        }
    }
}

// ---------------------------------------------------------------------------
// Gates: c_new = sig(f)*c_parent + sig(i)*tanh(g); h_new = sig(o)*tanh(c_new)
// ---------------------------------------------------------------------------
__device__ __forceinline__ float sigmoidf_(float x) {
    return 1.0f / (1.0f + expf(-x));
}

__global__ __launch_bounds__(256)
void cell_gates(const float* __restrict__ g_buf,
                const float* __restrict__ bih, const float* __restrict__ bhh,
                float* __restrict__ h_buf, float* __restrict__ c_buf,
                float* __restrict__ out, int layer, Level lv)
{
    const int slot = blockIdx.y;
    const int node = lv.n[slot];
    const int par  = lv.p[slot];

    const int e  = blockIdx.x * 256 + threadIdx.x;  // 0 .. B*H-1
    const int b  = e >> 10;
    const int hh = e & 1023;

    const float* g  = g_buf + (size_t)slot * B_ * G_ + (size_t)b * G_;
    const float* bi = bih + (size_t)layer * G_;
    const float* bh = bhh + (size_t)layer * G_;

    const float gi = g[hh]        + bi[hh]        + bh[hh];
    const float gf = g[1024 + hh] + bi[1024 + hh] + bh[1024 + hh];
    const float gg = g[2048 + hh] + bi[2048 + hh] + bh[2048 + hh];
    const float go = g[3072 + hh] + bi[3072 + hh] + bh[3072 + hh];

    const float cp = c_buf[((size_t)par * 2 + layer) * BH_ + e];

    const float c_new = sigmoidf_(gf) * cp + sigmoidf_(gi) * tanhf(gg);
    const float h_new = sigmoidf_(go) * tanhf(c_new);

    c_buf[((size_t)node * 2 + layer) * BH_ + e] = c_new;
    h_buf[((size_t)node * 2 + layer) * BH_ + e] = h_new;
    if (layer == 1) {
        out[(size_t)(node - 1) * BH_ + e] = h_new;
    }
}

// ---------------------------------------------------------------------------
extern "C" void kernel_launch(void* const* d_in, const int* in_sizes, int n_in,
                              void* d_out, int out_size, void* d_ws, size_t ws_size,
                              hipStream_t stream)
{
    const float* input  = (const float*)d_in[0];
    const float* bridge = (const float*)d_in[1];
    const float* Wih    = (const float*)d_in[2];
    const float* Whh    = (const float*)d_in[3];
    const float* bih    = (const float*)d_in[4];
    const float* bhh    = (const float*)d_in[5];
    float* out = (float*)d_out;

    // workspace: h[16][2][B][H] | c[16][2][B][H] | g[4 slots][B][4H]
    float* h_buf = (float*)d_ws;
    float* c_buf = h_buf + (size_t)16 * 2 * BH_;
    float* g_buf = c_buf + (size_t)16 * 2 * BH_;

    // zero initial state (node 0, both layers)
    hipMemsetAsync(h_buf, 0, (size_t)2 * BH_ * sizeof(float), stream);
    hipMemsetAsync(c_buf, 0, (size_t)2 * BH_ * sizeof(float), stream);

    // topological levels of PARENTS = [0,0,1,2,3,1,5,6,1,8,9,10,8,12,13,14]
    static const Level levels[6] = {
        { {1, 0, 0, 0},    {0, 0, 0, 0},    1 },
        { {2, 5, 8, 0},    {1, 1, 1, 0},    3 },
        { {3, 6, 9, 12},   {2, 5, 8, 8},    4 },
        { {4, 7, 10, 13},  {3, 6, 9, 12},   4 },
        { {11, 14, 0, 0},  {10, 13, 0, 0},  2 },
        { {15, 0, 0, 0},   {14, 0, 0, 0},   1 },
    };

    for (int li = 0; li < 6; ++li) {
        const Level& lv = levels[li];
        for (int layer = 0; layer < 2; ++layer) {
            dim3 ggrid(G_ / 64, B_ / 64, lv.cnt);
            cell_gemm<<<ggrid, 256, 0, stream>>>(input, bridge, Wih, Whh,
                                                 h_buf, g_buf, layer, lv);
            dim3 egrid(BH_ / 256, lv.cnt);
            cell_gates<<<egrid, 256, 0, stream>>>(g_buf, bih, bhh,
                                                  h_buf, c_buf, out, layer, lv);
        }
    }
}

// Round 2
// 1531.015 us; speedup vs baseline: 1.9499x; 1.9499x over previous
//
#include <hip/hip_runtime.h>
#include <stdint.h>

typedef unsigned short u16;
typedef short s16x8 __attribute__((ext_vector_type(8)));
typedef float fx16 __attribute__((ext_vector_type(16)));

#define B_   256
#define H_   1024
#define BH_  (B_ * H_)            // 262144
#define WPE  ((size_t)2 * 4096 * 2048)  // 16777216 elems per W pack buffer
#define XPE  ((size_t)15 * BH_)         // 3932160
#define HPE  ((size_t)32 * BH_)         // 8388608

struct Level { int n[4]; int p[4]; int cnt; };

__device__ __forceinline__ u16 bf16_rn(float x) {
    union { float f; uint32_t u; } v; v.f = x;
    return (u16)((v.u + 0x7FFFu + ((v.u >> 16) & 1u)) >> 16);
}
__device__ __forceinline__ float bf16_f(u16 h) {
    union { uint32_t u; float f; } v; v.u = ((uint32_t)h) << 16;
    return v.f;
}

// ---------------------------------------------------------------------------
// Pack W (f32 row-major [layer][4096][1024] ih,hh) into MFMA-B fragment order,
// split hi/lo bf16. Chunk index w = ((layer*4+gate)*32 + cg)*128 + k16;
// within chunk: lane l -> W[gate*1024+cg*32+(l&31)][k16*16+(l>>5)*8+e], e=0..7.
// One wave writes a contiguous 1KB chunk (lane*16B) -> perfect store coalescing.
// ---------------------------------------------------------------------------
__global__ __launch_bounds__(256)
void pack_weights(const float* __restrict__ Wih, const float* __restrict__ Whh,
                  u16* __restrict__ wp_hi, u16* __restrict__ wp_lo)
{
    const int gt = blockIdx.x * 256 + threadIdx.x;
    const int w = gt >> 6, lane = gt & 63;
    const int k16 = w & 127, cg = (w >> 7) & 31, gate = (w >> 12) & 3, layer = w >> 14;
    const int row = gate * 1024 + cg * 32 + (lane & 31);
    const int k = k16 * 16 + (lane >> 5) * 8;
    const float* src = (k < 1024)
        ? Wih + ((size_t)layer * 4096 + row) * 1024 + k
        : Whh + ((size_t)layer * 4096 + row) * 1024 + (k - 1024);
    const float4 v0 = *(const float4*)src;
    const float4 v1 = *(const float4*)(src + 4);
    const float a[8] = {v0.x, v0.y, v0.z, v0.w, v1.x, v1.y, v1.z, v1.w};
    union { u16 s[8]; uint4 v; } hi, lo;
    #pragma unroll
    for (int e = 0; e < 8; ++e) {
        hi.s[e] = bf16_rn(a[e]);
        lo.s[e] = bf16_rn(a[e] - bf16_f(hi.s[e]));
    }
    const size_t base = (size_t)w * 512 + (size_t)lane * 8;
    *(uint4*)(wp_hi + base) = hi.v;
    *(uint4*)(wp_lo + base) = lo.v;
}

// ---------------------------------------------------------------------------
// Pack x = [input | bridge] per node into MFMA-A fragment order, hi/lo bf16.
// Chunk w = (n1*8 + btile)*64 + k16; lane l -> x[b=btile*32+(l&31)][k16*16+(l>>5)*8+e]
// ---------------------------------------------------------------------------
__global__ __launch_bounds__(256)
void pack_x(const float* __restrict__ input, const float* __restrict__ bridge,
            u16* __restrict__ xp_hi, u16* __restrict__ xp_lo)
{
    const int gt = blockIdx.x * 256 + threadIdx.x;
    const int w = gt >> 6, lane = gt & 63;
    const int k16 = w & 63, btile = (w >> 6) & 7, n1 = w >> 9;   // n1 = node-1
    const int b = btile * 32 + (lane & 31);
    const int k = k16 * 16 + (lane >> 5) * 8;
    const float* src = (k < 512)
        ? input  + ((size_t)n1 * 256 + b) * 512 + k
        : bridge + ((size_t)n1 * 256 + b) * 512 + (k - 512);
    const float4 v0 = *(const float4*)src;
    const float4 v1 = *(const float4*)(src + 4);
    const float a[8] = {v0.x, v0.y, v0.z, v0.w, v1.x, v1.y, v1.z, v1.w};
    union { u16 s[8]; uint4 v; } hi, lo;
    #pragma unroll
    for (int e = 0; e < 8; ++e) {
        hi.s[e] = bf16_rn(a[e]);
        lo.s[e] = bf16_rn(a[e] - bf16_f(hi.s[e]));
    }
    const size_t base = (size_t)w * 512 + (size_t)lane * 8;
    *(uint4*)(xp_hi + base) = hi.v;
    *(uint4*)(xp_lo + base) = lo.v;
}

__global__ __launch_bounds__(256)
void bias_sum_k(const float* __restrict__ bih, const float* __restrict__ bhh,
                float* __restrict__ bs)
{
    const int i = blockIdx.x * 256 + threadIdx.x;
    if (i < 8192) bs[i] = bih[i] + bhh[i];
}

// ---------------------------------------------------------------------------
// MFMA GEMM: g[slot][gate][b][hh] = A(256x2048) @ W^T, split-bf16 3-pass.
// Register-direct (no LDS). 4 waves/block: wave -> (rowgroup, colgroup) 2x2.
// Wave tile: 32 batch x 32 hh x 4 gates, K=2048 via 128 x mfma_32x32x16_bf16.
// ---------------------------------------------------------------------------
__global__ __launch_bounds__(256)
void cell_gemm_mfma(const u16* __restrict__ wp_hi, const u16* __restrict__ wp_lo,
                    const u16* __restrict__ xp_hi, const u16* __restrict__ xp_lo,
                    const u16* __restrict__ hp_hi, const u16* __restrict__ hp_lo,
                    float* __restrict__ g_buf, int layer, Level lv)
{
    const int slot = blockIdx.z;
    const int node = lv.n[slot], par = lv.p[slot];
    const int tid = threadIdx.x;
    const int wv = tid >> 6, lane = tid & 63;
    const int btile = blockIdx.y * 2 + (wv >> 1);   // 0..7  (32 batch rows each)
    const int cg    = blockIdx.x * 2 + (wv & 1);    // 0..31 (32 hh cols each)

    // A-operand sources: seg0 = first 1024 K-cols, seg1 = last 1024
    const u16 *ahiB[2], *aloB[2];
    if (layer == 0) {
        ahiB[0] = xp_hi + (size_t)(node - 1) * BH_;
        aloB[0] = xp_lo + (size_t)(node - 1) * BH_;
        ahiB[1] = hp_hi + (size_t)(par * 2 + 0) * BH_;
        aloB[1] = hp_lo + (size_t)(par * 2 + 0) * BH_;
    } else {
        ahiB[0] = hp_hi + (size_t)(node * 2 + 0) * BH_;
        aloB[0] = hp_lo + (size_t)(node * 2 + 0) * BH_;
        ahiB[1] = hp_hi + (size_t)(par * 2 + 1) * BH_;
        aloB[1] = hp_lo + (size_t)(par * 2 + 1) * BH_;
    }
    const size_t aoff = (size_t)btile * 32768 + (size_t)lane * 8;   // + j*512

    const u16* whp[4]; const u16* wlp[4];
    #pragma unroll
    for (int g = 0; g < 4; ++g) {
        const size_t wb = ((((size_t)layer * 4 + g) * 32 + cg) * 128) * 512
                        + (size_t)lane * 8;                          // + k16g*512
        whp[g] = wp_hi + wb;
        wlp[g] = wp_lo + wb;
    }

    fx16 acc[4];
    #pragma unroll
    for (int g = 0; g < 4; ++g)
        #pragma unroll
        for (int r = 0; r < 16; ++r) acc[g][r] = 0.0f;

    #pragma unroll
    for (int seg = 0; seg < 2; ++seg) {
        const u16* Ah = ahiB[seg];
        const u16* Al = aloB[seg];
        const size_t wseg = (size_t)seg * 64 * 512;
        #pragma unroll 2
        for (int j = 0; j < 64; ++j) {
            const size_t ao = aoff + (size_t)j * 512;
            const s16x8 ah = *(const s16x8*)(Ah + ao);
            const s16x8 al = *(const s16x8*)(Al + ao);
            const size_t wo = wseg + (size_t)j * 512;
            #pragma unroll
            for (int g = 0; g < 4; ++g) {
                const s16x8 wh = *(const s16x8*)(whp[g] + wo);
                const s16x8 wl = *(const s16x8*)(wlp[g] + wo);
                acc[g] = __builtin_amdgcn_mfma_f32_32x32x16_bf16(ah, wh, acc[g], 0, 0, 0);
                acc[g] = __builtin_amdgcn_mfma_f32_32x32x16_bf16(al, wh, acc[g], 0, 0, 0);
                acc[g] = __builtin_amdgcn_mfma_f32_32x32x16_bf16(ah, wl, acc[g], 0, 0, 0);
            }
        }
    }

    // C/D layout (m74/m101 verified): col = lane&31, row = (r&3)+8*(r>>2)+4*(lane>>5)
    const int hh = cg * 32 + (lane & 31);
    const int b0 = btile * 32 + 4 * (lane >> 5);
    #pragma unroll
    for (int g = 0; g < 4; ++g) {
        float* gp = g_buf + (((size_t)slot * 4 + g) * 256) * 1024 + hh;
        #pragma unroll
        for (int r = 0; r < 16; ++r) {
            const int brow = b0 + (r & 3) + 8 * (r >> 2);
            gp[(size_t)brow * 1024] = acc[g][r];
        }
    }
}

// ---------------------------------------------------------------------------
// Gates: thread -> 8 consecutive h at one b. Writes c (f32), h packed hi/lo
// (same fragment order the GEMM A-path reads), and out for layer 1.
// ---------------------------------------------------------------------------
__global__ __launch_bounds__(256)
void cell_gates(const float* __restrict__ g_buf, const float* __restrict__ bsum,
                float* __restrict__ c_buf, u16* __restrict__ hp_hi,
                u16* __restrict__ hp_lo, float* __restrict__ out,
                int layer, Level lv)
{
    const int slot = blockIdx.y;
    const int node = lv.n[slot], par = lv.p[slot];
    const int i = blockIdx.x * 256 + threadIdx.x;    // 0..32767 chunk index
    const int lane = i & 63;
    const int k16 = (i >> 6) & 63;
    const int btile = i >> 12;
    const int b  = btile * 32 + (lane & 31);
    const int h0 = k16 * 16 + (lane >> 5) * 8;

    float gv[4][8];
    #pragma unroll
    for (int g = 0; g < 4; ++g) {
        const float* gp = g_buf + (((size_t)slot * 4 + g) * 256 + b) * 1024 + h0;
        const float* bs = bsum + (size_t)layer * 4096 + g * 1024 + h0;
        const float4 a0 = *(const float4*)gp;
        const float4 a1 = *(const float4*)(gp + 4);
        const float4 c0 = *(const float4*)bs;
        const float4 c1 = *(const float4*)(bs + 4);
        gv[g][0] = a0.x + c0.x; gv[g][1] = a0.y + c0.y;
        gv[g][2] = a0.z + c0.z; gv[g][3] = a0.w + c0.w;
        gv[g][4] = a1.x + c1.x; gv[g][5] = a1.y + c1.y;
        gv[g][6] = a1.z + c1.z; gv[g][7] = a1.w + c1.w;
    }

    const float* cp = c_buf + (size_t)(par * 2 + layer) * BH_ + (size_t)b * 1024 + h0;
    float*       cn = c_buf + (size_t)(node * 2 + layer) * BH_ + (size_t)b * 1024 + h0;
    const float4 cp0 = *(const float4*)cp;
    const float4 cp1 = *(const float4*)(cp + 4);
    const float cpv[8] = {cp0.x, cp0.y, cp0.z, cp0.w, cp1.x, cp1.y, cp1.z, cp1.w};

    float cnv[8], hnv[8];
    #pragma unroll
    for (int e = 0; e < 8; ++e) {
        const float I  = 1.0f / (1.0f + expf(-gv[0][e]));
        const float F  = 1.0f / (1.0f + expf(-gv[1][e]));
        const float GG = tanhf(gv[2][e]);
        const float O  = 1.0f / (1.0f + expf(-gv[3][e]));
        const float c_new = F * cpv[e] + I * GG;
        cnv[e] = c_new;
        hnv[e] = O * tanhf(c_new);
    }

    *(float4*)cn       = make_float4(cnv[0], cnv[1], cnv[2], cnv[3]);
    *(float4*)(cn + 4) = make_float4(cnv[4], cnv[5], cnv[6], cnv[7]);

    union { u16 s[8]; uint4 v; } hi, lo;
    #pragma unroll
    for (int e = 0; e < 8; ++e) {
        hi.s[e] = bf16_rn(hnv[e]);
        lo.s[e] = bf16_rn(hnv[e] - bf16_f(hi.s[e]));
    }
    const size_t hb = (size_t)(node * 2 + layer) * BH_ + (size_t)i * 8;
    *(uint4*)(hp_hi + hb) = hi.v;
    *(uint4*)(hp_lo + hb) = lo.v;

    if (layer == 1) {
        float* op = out + (size_t)(node - 1) * BH_ + (size_t)b * 1024 + h0;
        *(float4*)op       = make_float4(hnv[0], hnv[1], hnv[2], hnv[3]);
        *(float4*)(op + 4) = make_float4(hnv[4], hnv[5], hnv[6], hnv[7]);
    }
}

// ---------------------------------------------------------------------------
extern "C" void kernel_launch(void* const* d_in, const int* in_sizes, int n_in,
                              void* d_out, int out_size, void* d_ws, size_t ws_size,
                              hipStream_t stream)
{
    const float* input  = (const float*)d_in[0];
    const float* bridge = (const float*)d_in[1];
    const float* Wih    = (const float*)d_in[2];
    const float* Whh    = (const float*)d_in[3];
    const float* bih    = (const float*)d_in[4];
    const float* bhh    = (const float*)d_in[5];
    float* out = (float*)d_out;

    // workspace carve-up (~167 MB)
    u16* wp_hi = (u16*)d_ws;
    u16* wp_lo = wp_hi + WPE;
    u16* xp_hi = wp_lo + WPE;
    u16* xp_lo = xp_hi + XPE;
    u16* hp_hi = xp_lo + XPE;
    u16* hp_lo = hp_hi + HPE;
    float* c_buf = (float*)(hp_lo + HPE);
    float* g_buf = c_buf + (size_t)8388608;
    float* bsum  = g_buf + (size_t)4194304;

    // zero node-0 state (both layers)
    hipMemsetAsync(hp_hi, 0, (size_t)2 * BH_ * sizeof(u16), stream);
    hipMemsetAsync(hp_lo, 0, (size_t)2 * BH_ * sizeof(u16), stream);
    hipMemsetAsync(c_buf, 0, (size_t)2 * BH_ * sizeof(float), stream);

    bias_sum_k<<<32, 256, 0, stream>>>(bih, bhh, bsum);
    pack_weights<<<8192, 256, 0, stream>>>(Wih, Whh, wp_hi, wp_lo);
    pack_x<<<1920, 256, 0, stream>>>(input, bridge, xp_hi, xp_lo);

    static const Level levels[6] = {
        { {1, 0, 0, 0},    {0, 0, 0, 0},    1 },
        { {2, 5, 8, 0},    {1, 1, 1, 0},    3 },
        { {3, 6, 9, 12},   {2, 5, 8, 8},    4 },
        { {4, 7, 10, 13},  {3, 6, 9, 12},   4 },
        { {11, 14, 0, 0},  {10, 13, 0, 0},  2 },
        { {15, 0, 0, 0},   {14, 0, 0, 0},   1 },
    };

    for (int li = 0; li < 6; ++li) {
        const Level& lv = levels[li];
        for (int layer = 0; layer < 2; ++layer) {
            cell_gemm_mfma<<<dim3(16, 4, lv.cnt), 256, 0, stream>>>(
                wp_hi, wp_lo, xp_hi, xp_lo, hp_hi, hp_lo, g_buf, layer, lv);
            cell_gates<<<dim3(128, lv.cnt), 256, 0, stream>>>(
                g_buf, bsum, c_buf, hp_hi, hp_lo, out, layer, lv);
        }
    }
}

// Round 3
// 503.837 us; speedup vs baseline: 5.9251x; 3.0387x over previous
//
#include <hip/hip_runtime.h>
#include <stdint.h>

typedef unsigned short u16;
typedef short s16x8 __attribute__((ext_vector_type(8)));
typedef float fx16 __attribute__((ext_vector_type(16)));

#define B_   256
#define H_   1024
#define BH_  (B_ * H_)                  // 262144
#define WPE  ((size_t)2 * 4096 * 2048)  // 16777216 elems (W hi pack)
#define XPE  ((size_t)15 * BH_)         // 3932160
#define HPE  ((size_t)32 * BH_)         // 8388608

struct Stage { int node[8]; int par[8]; int layer[8]; int cnt; };

__device__ __forceinline__ u16 bf16_rn(float x) {
    union { float f; uint32_t u; } v; v.f = x;
    return (u16)((v.u + 0x7FFFu + ((v.u >> 16) & 1u)) >> 16);
}
__device__ __forceinline__ float bf16_f(u16 h) {
    union { uint32_t u; float f; } v; v.u = ((uint32_t)h) << 16;
    return v.f;
}

// ---------------------------------------------------------------------------
// Pack W (f32 [layer][4096][1024] ih,hh) into MFMA-B fragment order, hi bf16
// only (2-pass scheme). Chunk w = ((layer*4+gate)*32 + cg)*128 + k16;
// lane l -> W[gate*1024+cg*32+(l&31)][k16*16+(l>>5)*8+e], e=0..7.
// ---------------------------------------------------------------------------
__global__ __launch_bounds__(256)
void pack_weights(const float* __restrict__ Wih, const float* __restrict__ Whh,
                  u16* __restrict__ wp_hi)
{
    const int gt = blockIdx.x * 256 + threadIdx.x;
    const int w = gt >> 6, lane = gt & 63;
    const int k16 = w & 127, cg = (w >> 7) & 31, gate = (w >> 12) & 3, layer = w >> 14;
    const int row = gate * 1024 + cg * 32 + (lane & 31);
    const int k = k16 * 16 + (lane >> 5) * 8;
    const float* src = (k < 1024)
        ? Wih + ((size_t)layer * 4096 + row) * 1024 + k
        : Whh + ((size_t)layer * 4096 + row) * 1024 + (k - 1024);
    const float4 v0 = *(const float4*)src;
    const float4 v1 = *(const float4*)(src + 4);
    const float a[8] = {v0.x, v0.y, v0.z, v0.w, v1.x, v1.y, v1.z, v1.w};
    union { u16 s[8]; uint4 v; } hi;
    #pragma unroll
    for (int e = 0; e < 8; ++e) hi.s[e] = bf16_rn(a[e]);
    *(uint4*)(wp_hi + (size_t)w * 512 + (size_t)lane * 8) = hi.v;
}

// ---------------------------------------------------------------------------
// Pack x = [input | bridge] per node, MFMA-A fragment order, hi/lo bf16.
// ---------------------------------------------------------------------------
__global__ __launch_bounds__(256)
void pack_x(const float* __restrict__ input, const float* __restrict__ bridge,
            u16* __restrict__ xp_hi, u16* __restrict__ xp_lo)
{
    const int gt = blockIdx.x * 256 + threadIdx.x;
    const int w = gt >> 6, lane = gt & 63;
    const int k16 = w & 63, btile = (w >> 6) & 7, n1 = w >> 9;
    const int b = btile * 32 + (lane & 31);
    const int k = k16 * 16 + (lane >> 5) * 8;
    const float* src = (k < 512)
        ? input  + ((size_t)n1 * 256 + b) * 512 + k
        : bridge + ((size_t)n1 * 256 + b) * 512 + (k - 512);
    const float4 v0 = *(const float4*)src;
    const float4 v1 = *(const float4*)(src + 4);
    const float a[8] = {v0.x, v0.y, v0.z, v0.w, v1.x, v1.y, v1.z, v1.w};
    union { u16 s[8]; uint4 v; } hi, lo;
    #pragma unroll
    for (int e = 0; e < 8; ++e) {
        hi.s[e] = bf16_rn(a[e]);
        lo.s[e] = bf16_rn(a[e] - bf16_f(hi.s[e]));
    }
    const size_t base = (size_t)w * 512 + (size_t)lane * 8;
    *(uint4*)(xp_hi + base) = hi.v;
    *(uint4*)(xp_lo + base) = lo.v;
}

__global__ __launch_bounds__(256)
void bias_sum_k(const float* __restrict__ bih, const float* __restrict__ bhh,
                float* __restrict__ bs)
{
    const int i = blockIdx.x * 256 + threadIdx.x;
    if (i < 8192) bs[i] = bih[i] + bhh[i];
}

// ---------------------------------------------------------------------------
// Stage GEMM: for each cell in stage, g[cell] (256x4096) = A(256x2048) @ W^T.
// 2-pass split-bf16: ah*wh + al*wh. Block = 128 batch x 128 cols (one gate),
// 4 waves (one 32-row btile each, 4x 32x32 col frags). W chunk (128 cols x
// 64 K) double-buffered in LDS via global_load_lds; A register-direct (L2).
// blocks/cell = 64; grid.x = cnt*64; cell = bid % cnt (spreads cells across
// XCDs so each XCD's L2 caches ~1-2 cells' A).
// ---------------------------------------------------------------------------
__global__ __launch_bounds__(256)
void cell_gemm_mfma(const u16* __restrict__ wp_hi,
                    const u16* __restrict__ xp_hi, const u16* __restrict__ xp_lo,
                    const u16* __restrict__ hp_hi, const u16* __restrict__ hp_lo,
                    float* __restrict__ g_buf, Stage st)
{
    __shared__ u16 Wl[2][8192];   // [buf][cg(4)][k16(4)][512] = 2 x 16KB

    const int bid  = blockIdx.x;
    const int cell = bid % st.cnt;
    const int tile = bid / st.cnt;          // 0..63
    const int node = st.node[cell], par = st.par[cell], layer = st.layer[cell];
    const int mtile = tile & 1;
    const int ntile = tile >> 1;            // 0..31
    const int gate  = ntile >> 3;
    const int cgb   = (ntile & 7) * 4;
    const int tid = threadIdx.x, wv = tid >> 6, lane = tid & 63;
    const int btile = mtile * 4 + wv;

    // A segment bases (seg0 = K 0..1023, seg1 = K 1024..2047)
    const u16 *Ah0, *Al0, *Ah1, *Al1;
    if (layer == 0) {
        Ah0 = xp_hi + (size_t)(node - 1) * BH_;
        Al0 = xp_lo + (size_t)(node - 1) * BH_;
        Ah1 = hp_hi + (size_t)(par * 2 + 0) * BH_;
        Al1 = hp_lo + (size_t)(par * 2 + 0) * BH_;
    } else {
        Ah0 = hp_hi + (size_t)(node * 2 + 0) * BH_;
        Al0 = hp_lo + (size_t)(node * 2 + 0) * BH_;
        Ah1 = hp_hi + (size_t)(par * 2 + 1) * BH_;
        Al1 = hp_lo + (size_t)(par * 2 + 1) * BH_;
    }
    const size_t aoff = (size_t)btile * 32768 + (size_t)lane * 8;

    // W run base (elems). cg c run starts at wsb + c*65536; k16-chunk t*4
    // starts at +t*2048 within a run. Runs are contiguous per cg.
    const size_t wsb = (size_t)((layer * 4 + gate) * 32 + cgb) * 128 * 512;

    // stage chunk T into LDS buf: 4 runs (cg 0..3) x 2048 elems (4KB each);
    // per run: 256 threads x 16B, per-lane-consecutive -> coalesced.
    #define STAGE(T, BUF) do {                                                 \
        const size_t kof_ = (size_t)(T) * 2048;                                \
        _Pragma("unroll")                                                      \
        for (int i_ = 0; i_ < 4; ++i_) {                                       \
            __builtin_amdgcn_global_load_lds(                                  \
                (const __attribute__((address_space(1))) void*)                \
                    (wp_hi + wsb + (size_t)i_ * 65536 + kof_ + (size_t)tid * 8),\
                (__attribute__((address_space(3))) void*)                      \
                    (&Wl[BUF][i_ * 2048 + wv * 512]),                          \
                16, 0, 0);                                                     \
        }                                                                      \
    } while (0)

    #define COMPUTE(T, BUF) do {                                               \
        const u16* Ah_ = ((T) < 16) ? Ah0 : Ah1;                               \
        const u16* Al_ = ((T) < 16) ? Al0 : Al1;                               \
        const size_t ab_ = aoff + (size_t)((T) & 15) * 2048;                   \
        _Pragma("unroll")                                                      \
        for (int kk_ = 0; kk_ < 4; ++kk_) {                                    \
            const s16x8 ah_ = *(const s16x8*)(Ah_ + ab_ + kk_ * 512);          \
            const s16x8 al_ = *(const s16x8*)(Al_ + ab_ + kk_ * 512);          \
            _Pragma("unroll")                                                  \
            for (int c_ = 0; c_ < 4; ++c_) {                                   \
                const s16x8 wh_ = *(const s16x8*)                              \
                    (&Wl[BUF][c_ * 2048 + kk_ * 512 + lane * 8]);              \
                acc[c_] = __builtin_amdgcn_mfma_f32_32x32x16_bf16(             \
                    ah_, wh_, acc[c_], 0, 0, 0);                               \
                acc[c_] = __builtin_amdgcn_mfma_f32_32x32x16_bf16(             \
                    al_, wh_, acc[c_], 0, 0, 0);                               \
            }                                                                  \
        }                                                                      \
    } while (0)

    fx16 acc[4];
    #pragma unroll
    for (int c = 0; c < 4; ++c)
        #pragma unroll
        for (int r = 0; r < 16; ++r) acc[c][r] = 0.0f;

    STAGE(0, 0);
    __syncthreads();

    #pragma unroll 1
    for (int tt = 0; tt < 16; ++tt) {
        const int t0 = tt * 2;
        STAGE(t0 + 1, 1);
        COMPUTE(t0, 0);
        __syncthreads();
        if (t0 + 2 < 32) STAGE(t0 + 2, 0);
        COMPUTE(t0 + 1, 1);
        __syncthreads();
    }
    #undef STAGE
    #undef COMPUTE

    // C/D layout: col = lane&31, row = (r&3) + 8*(r>>2) + 4*(lane>>5)
    const int b0 = btile * 32 + 4 * (lane >> 5);
    #pragma unroll
    for (int c = 0; c < 4; ++c) {
        float* gp = g_buf + ((size_t)(cell * 4 + gate) * 256) * 1024
                  + (cgb + c) * 32 + (lane & 31);
        #pragma unroll
        for (int r = 0; r < 16; ++r) {
            const int brow = b0 + (r & 3) + 8 * (r >> 2);
            gp[(size_t)brow * 1024] = acc[c][r];
        }
    }
}

// ---------------------------------------------------------------------------
// Gates epilogue per stage.
// ---------------------------------------------------------------------------
__global__ __launch_bounds__(256)
void cell_gates(const float* __restrict__ g_buf, const float* __restrict__ bsum,
                float* __restrict__ c_buf, u16* __restrict__ hp_hi,
                u16* __restrict__ hp_lo, float* __restrict__ out, Stage st)
{
    const int cell = blockIdx.y;
    const int node = st.node[cell], par = st.par[cell], layer = st.layer[cell];
    const int i = blockIdx.x * 256 + threadIdx.x;    // 0..32767
    const int lane = i & 63;
    const int k16 = (i >> 6) & 63;
    const int btile = i >> 12;
    const int b  = btile * 32 + (lane & 31);
    const int h0 = k16 * 16 + (lane >> 5) * 8;

    float gv[4][8];
    #pragma unroll
    for (int g = 0; g < 4; ++g) {
        const float* gp = g_buf + (((size_t)cell * 4 + g) * 256 + b) * 1024 + h0;
        const float* bs = bsum + (size_t)layer * 4096 + g * 1024 + h0;
        const float4 a0 = *(const float4*)gp;
        const float4 a1 = *(const float4*)(gp + 4);
        const float4 c0 = *(const float4*)bs;
        const float4 c1 = *(const float4*)(bs + 4);
        gv[g][0] = a0.x + c0.x; gv[g][1] = a0.y + c0.y;
        gv[g][2] = a0.z + c0.z; gv[g][3] = a0.w + c0.w;
        gv[g][4] = a1.x + c1.x; gv[g][5] = a1.y + c1.y;
        gv[g][6] = a1.z + c1.z; gv[g][7] = a1.w + c1.w;
    }

    const float* cp = c_buf + (size_t)(par * 2 + layer) * BH_ + (size_t)b * 1024 + h0;
    float*       cn = c_buf + (size_t)(node * 2 + layer) * BH_ + (size_t)b * 1024 + h0;
    const float4 cp0 = *(const float4*)cp;
    const float4 cp1 = *(const float4*)(cp + 4);
    const float cpv[8] = {cp0.x, cp0.y, cp0.z, cp0.w, cp1.x, cp1.y, cp1.z, cp1.w};

    float cnv[8], hnv[8];
    #pragma unroll
    for (int e = 0; e < 8; ++e) {
        const float I  = 1.0f / (1.0f + expf(-gv[0][e]));
        const float F  = 1.0f / (1.0f + expf(-gv[1][e]));
        const float GG = tanhf(gv[2][e]);
        const float O  = 1.0f / (1.0f + expf(-gv[3][e]));
        const float c_new = F * cpv[e] + I * GG;
        cnv[e] = c_new;
        hnv[e] = O * tanhf(c_new);
    }

    *(float4*)cn       = make_float4(cnv[0], cnv[1], cnv[2], cnv[3]);
    *(float4*)(cn + 4) = make_float4(cnv[4], cnv[5], cnv[6], cnv[7]);

    union { u16 s[8]; uint4 v; } hi, lo;
    #pragma unroll
    for (int e = 0; e < 8; ++e) {
        hi.s[e] = bf16_rn(hnv[e]);
        lo.s[e] = bf16_rn(hnv[e] - bf16_f(hi.s[e]));
    }
    const size_t hb = (size_t)(node * 2 + layer) * BH_ + (size_t)i * 8;
    *(uint4*)(hp_hi + hb) = hi.v;
    *(uint4*)(hp_lo + hb) = lo.v;

    if (layer == 1) {
        float* op = out + (size_t)(node - 1) * BH_ + (size_t)b * 1024 + h0;
        *(float4*)op       = make_float4(hnv[0], hnv[1], hnv[2], hnv[3]);
        *(float4*)(op + 4) = make_float4(hnv[4], hnv[5], hnv[6], hnv[7]);
    }
}

// ---------------------------------------------------------------------------
extern "C" void kernel_launch(void* const* d_in, const int* in_sizes, int n_in,
                              void* d_out, int out_size, void* d_ws, size_t ws_size,
                              hipStream_t stream)
{
    const float* input  = (const float*)d_in[0];
    const float* bridge = (const float*)d_in[1];
    const float* Wih    = (const float*)d_in[2];
    const float* Whh    = (const float*)d_in[3];
    const float* bih    = (const float*)d_in[4];
    const float* bhh    = (const float*)d_in[5];
    float* out = (float*)d_out;

    // workspace: wp_hi 32MB | xp hi/lo 15MB | hp hi/lo 32MB | c 32MB | g 32MB
    u16* wp_hi = (u16*)d_ws;
    u16* xp_hi = wp_hi + WPE;
    u16* xp_lo = xp_hi + XPE;
    u16* hp_hi = xp_lo + XPE;
    u16* hp_lo = hp_hi + HPE;
    float* c_buf = (float*)(hp_lo + HPE);
    float* g_buf = c_buf + (size_t)8388608;
    float* bsum  = g_buf + (size_t)8388608;

    hipMemsetAsync(hp_hi, 0, (size_t)2 * BH_ * sizeof(u16), stream);
    hipMemsetAsync(hp_lo, 0, (size_t)2 * BH_ * sizeof(u16), stream);
    hipMemsetAsync(c_buf, 0, (size_t)2 * BH_ * sizeof(float), stream);

    bias_sum_k<<<32, 256, 0, stream>>>(bih, bhh, bsum);
    pack_weights<<<8192, 256, 0, stream>>>(Wih, Whh, wp_hi);
    pack_x<<<1920, 256, 0, stream>>>(input, bridge, xp_hi, xp_lo);

    // Wavefront schedule: stage T holds all cells (node,layer) with
    // depth(node)+layer == T; PARENTS=[0,0,1,2,3,1,5,6,1,8,9,10,8,12,13,14]
    static const Stage stages[7] = {
        { {1},                      {0},                      {0},                      1 },
        { {1,2,5,8},                {0,1,1,1},                {1,0,0,0},                4 },
        { {2,5,8,3,6,9,12},         {1,1,1,2,5,8,8},          {1,1,1,0,0,0,0},          7 },
        { {3,6,9,12,4,7,10,13},     {2,5,8,8,3,6,9,12},       {1,1,1,1,0,0,0,0},        8 },
        { {4,7,10,13,11,14},        {3,6,9,12,10,13},         {1,1,1,1,0,0},            6 },
        { {11,14,15},               {10,13,14},               {1,1,0},                  3 },
        { {15},                     {14},                     {1},                      1 },
    };

    for (int s = 0; s < 7; ++s) {
        cell_gemm_mfma<<<dim3(stages[s].cnt * 64), 256, 0, stream>>>(
            wp_hi, xp_hi, xp_lo, hp_hi, hp_lo, g_buf, stages[s]);
        cell_gates<<<dim3(128, stages[s].cnt), 256, 0, stream>>>(
            g_buf, bsum, c_buf, hp_hi, hp_lo, out, stages[s]);
    }
}

// Round 4
// 391.297 us; speedup vs baseline: 7.6292x; 1.2876x over previous
//
#include <hip/hip_runtime.h>
#include <stdint.h>

typedef unsigned short u16;
typedef uint32_t u32;
typedef short s16x8 __attribute__((ext_vector_type(8)));
typedef float fx16 __attribute__((ext_vector_type(16)));

#define B_   256
#define H_   1024
#define BH_  (B_ * H_)                  // 262144
#define WPE  ((size_t)2 * 4096 * 2048)  // W pack elems (hi only)
#define XPE  ((size_t)15 * BH_)
#define HPE  ((size_t)32 * BH_)

struct Stage { int node[8]; int par[8]; int layer[8]; int cnt; };

__device__ __forceinline__ u16 bf16_rn(float x) {
    union { float f; u32 u; } v; v.f = x;
    return (u16)((v.u + 0x7FFFu + ((v.u >> 16) & 1u)) >> 16);
}
__device__ __forceinline__ float sigf(float x) {
    return __builtin_amdgcn_rcpf(1.0f + __expf(-x));
}
__device__ __forceinline__ float tanh_f(float x) {
    // (e^2x - 1)/(e^2x + 1); saturates correctly at +/-inf
    return 1.0f - 2.0f * __builtin_amdgcn_rcpf(1.0f + __expf(2.0f * x));
}

// ---------------------------------------------------------------------------
// Pack W into MFMA-B fragment order, bf16 (hi only — 1-pass scheme).
// Chunk w = ((layer*4+gate)*32 + cg)*128 + k16;
// lane l -> W[gate*1024+cg*32+(l&31)][k16*16+(l>>5)*8+e], e=0..7.
// ---------------------------------------------------------------------------
__global__ __launch_bounds__(256)
void pack_weights(const float* __restrict__ Wih, const float* __restrict__ Whh,
                  u16* __restrict__ wp)
{
    const int gt = blockIdx.x * 256 + threadIdx.x;
    const int w = gt >> 6, lane = gt & 63;
    const int k16 = w & 127, cg = (w >> 7) & 31, gate = (w >> 12) & 3, layer = w >> 14;
    const int row = gate * 1024 + cg * 32 + (lane & 31);
    const int k = k16 * 16 + (lane >> 5) * 8;
    const float* src = (k < 1024)
        ? Wih + ((size_t)layer * 4096 + row) * 1024 + k
        : Whh + ((size_t)layer * 4096 + row) * 1024 + (k - 1024);
    const float4 v0 = *(const float4*)src;
    const float4 v1 = *(const float4*)(src + 4);
    const float a[8] = {v0.x, v0.y, v0.z, v0.w, v1.x, v1.y, v1.z, v1.w};
    union { u16 s[8]; uint4 v; } hi;
    #pragma unroll
    for (int e = 0; e < 8; ++e) hi.s[e] = bf16_rn(a[e]);
    *(uint4*)(wp + (size_t)w * 512 + (size_t)lane * 8) = hi.v;
}

// ---------------------------------------------------------------------------
// Pack x = [input | bridge] per node, MFMA-A fragment order, bf16 hi only.
// ---------------------------------------------------------------------------
__global__ __launch_bounds__(256)
void pack_x(const float* __restrict__ input, const float* __restrict__ bridge,
            u16* __restrict__ xp)
{
    const int gt = blockIdx.x * 256 + threadIdx.x;
    const int w = gt >> 6, lane = gt & 63;
    const int k16 = w & 63, btile = (w >> 6) & 7, n1 = w >> 9;
    const int b = btile * 32 + (lane & 31);
    const int k = k16 * 16 + (lane >> 5) * 8;
    const float* src = (k < 512)
        ? input  + ((size_t)n1 * 256 + b) * 512 + k
        : bridge + ((size_t)n1 * 256 + b) * 512 + (k - 512);
    const float4 v0 = *(const float4*)src;
    const float4 v1 = *(const float4*)(src + 4);
    const float a[8] = {v0.x, v0.y, v0.z, v0.w, v1.x, v1.y, v1.z, v1.w};
    union { u16 s[8]; uint4 v; } hi;
    #pragma unroll
    for (int e = 0; e < 8; ++e) hi.s[e] = bf16_rn(a[e]);
    *(uint4*)(xp + (size_t)w * 512 + (size_t)lane * 8) = hi.v;
}

__global__ __launch_bounds__(256)
void bias_sum_k(const float* __restrict__ bih, const float* __restrict__ bhh,
                float* __restrict__ bs)
{
    const int i = blockIdx.x * 256 + threadIdx.x;
    if (i < 8192) bs[i] = bih[i] + bhh[i];
}

// ---------------------------------------------------------------------------
// Fused cell: GEMM (1-pass bf16) + gates + packed-h store.
// Block = 128 threads (2 waves). Block tile: 128 batch x 32 hh x 4 gates.
// Wave: 2 btiles (64 b) x 32 hh x 4 gates -> 8 fx16 accs.
// W (4 gate-runs x 32 cols x 64 K) double-buffered in LDS (2 x 16 KB) via
// global_load_lds; A register-direct (L2-resident, 0.5 MB/cell).
// XCD swizzle: tile = ((bid&7)<<3)|((bid>>3)&7) -> XCD x owns hhblk 4x..4x+3
// for every cell/stage; per-XCD W slice = 4 MB = its L2.
// ---------------------------------------------------------------------------
__global__ __launch_bounds__(128)
void cell_fused(const u16* __restrict__ wp, const u16* __restrict__ xp,
                u16* __restrict__ hp, float* __restrict__ c_buf,
                const float* __restrict__ bsum, float* __restrict__ out,
                Stage st)
{
    __shared__ u16 Wl[2][8192];   // [buf][gate(4)][k16(4)][512] = 2 x 16KB

    const int bid  = blockIdx.x;
    const int cell = bid >> 6;
    const int u    = bid & 63;
    const int tile = ((u & 7) << 3) | (u >> 3);
    const int hhblk = tile >> 1;            // 0..31
    const int mtile = tile & 1;             // 0..1
    const int node = st.node[cell], par = st.par[cell], layer = st.layer[cell];
    const int tid = threadIdx.x, wv = tid >> 6, lane = tid & 63;
    const int bt0 = mtile * 4 + wv * 2;     // first of this wave's 2 btiles

    // A segment bases (seg0 = K 0..1023, seg1 = K 1024..2047)
    const u16 *A0, *A1;
    if (layer == 0) {
        A0 = xp + (size_t)(node - 1) * BH_;
        A1 = hp + (size_t)(par * 2 + 0) * BH_;
    } else {
        A0 = hp + (size_t)(node * 2 + 0) * BH_;
        A1 = hp + (size_t)(par * 2 + 1) * BH_;
    }

    size_t wbase[4];
    #pragma unroll
    for (int g = 0; g < 4; ++g)
        wbase[g] = (size_t)((layer * 4 + g) * 32 + hhblk) * 65536;

    #define STAGE(T, BUF) do {                                                 \
        _Pragma("unroll")                                                      \
        for (int g_ = 0; g_ < 4; ++g_) {                                       \
            _Pragma("unroll")                                                  \
            for (int p_ = 0; p_ < 2; ++p_) {                                   \
                __builtin_amdgcn_global_load_lds(                              \
                    (const __attribute__((address_space(1))) void*)            \
                        (wp + wbase[g_] + (size_t)(T) * 2048                   \
                         + (size_t)wv * 1024 + p_ * 512 + (size_t)lane * 8),   \
                    (__attribute__((address_space(3))) void*)                  \
                        (&Wl[BUF][g_ * 2048 + wv * 1024 + p_ * 512]),          \
                    16, 0, 0);                                                 \
            }                                                                  \
        }                                                                      \
    } while (0)

    #define COMPUTE(T, BUF) do {                                               \
        const u16* A_ = ((T) < 16) ? A0 : A1;                                  \
        const size_t ab_ = (size_t)((T) & 15) * 2048 + (size_t)lane * 8;       \
        _Pragma("unroll")                                                      \
        for (int kk_ = 0; kk_ < 4; ++kk_) {                                    \
            const s16x8 a0_ = *(const s16x8*)(A_ + (size_t)bt0 * 32768         \
                                              + ab_ + kk_ * 512);              \
            const s16x8 a1_ = *(const s16x8*)(A_ + (size_t)(bt0 + 1) * 32768   \
                                              + ab_ + kk_ * 512);              \
            _Pragma("unroll")                                                  \
            for (int g_ = 0; g_ < 4; ++g_) {                                   \
                const s16x8 wh_ = *(const s16x8*)                              \
                    (&Wl[BUF][g_ * 2048 + kk_ * 512 + lane * 8]);              \
                acc[0][g_] = __builtin_amdgcn_mfma_f32_32x32x16_bf16(          \
                    a0_, wh_, acc[0][g_], 0, 0, 0);                            \
                acc[1][g_] = __builtin_amdgcn_mfma_f32_32x32x16_bf16(          \
                    a1_, wh_, acc[1][g_], 0, 0, 0);                            \
            }                                                                  \
        }                                                                      \
    } while (0)

    fx16 acc[2][4];
    #pragma unroll
    for (int q = 0; q < 2; ++q)
        #pragma unroll
        for (int g = 0; g < 4; ++g)
            #pragma unroll
            for (int r = 0; r < 16; ++r) acc[q][g][r] = 0.0f;

    STAGE(0, 0);
    __syncthreads();

    #pragma unroll 1
    for (int tt = 0; tt < 16; ++tt) {
        const int t0 = tt * 2;
        STAGE(t0 + 1, 1);
        COMPUTE(t0, 0);
        __syncthreads();
        if (t0 + 2 < 32) STAGE(t0 + 2, 0);
        COMPUTE(t0 + 1, 1);
        __syncthreads();
    }
    #undef STAGE
    #undef COMPUTE

    // ---- fused gates epilogue (C/D layout: col=lane&31, row=(r&3)+8*(r>>2)+4*(lane>>5))
    const int col  = lane & 31;
    const int colg = hhblk * 32 + col;
    float bs4[4];
    #pragma unroll
    for (int g = 0; g < 4; ++g)
        bs4[g] = bsum[layer * 4096 + g * 1024 + colg];

    const float* cpar_base = c_buf + (size_t)(par * 2 + layer) * BH_ + colg;
    float*       cnew_base = c_buf + (size_t)(node * 2 + layer) * BH_ + colg;
    float*       out_base  = out + (size_t)(node - 1) * BH_ + colg;

    u32* hb = (u32*)(&Wl[0][0]);   // reuse retired W LDS: 4 quadrants x 32x33 u32

    #pragma unroll
    for (int q = 0; q < 2; ++q) {
        const int bt = bt0 + q;
        u32* hq = hb + (wv * 2 + q) * 1056;
        #pragma unroll
        for (int r = 0; r < 16; ++r) {
            const int rl = 4 * (lane >> 5) + (r & 3) + 8 * (r >> 2);
            const size_t row = (size_t)(bt * 32 + rl) * 1024;
            const float gi = acc[q][0][r] + bs4[0];
            const float gf = acc[q][1][r] + bs4[1];
            const float gg = acc[q][2][r] + bs4[2];
            const float go = acc[q][3][r] + bs4[3];
            const float cp = cpar_base[row];
            const float cn = sigf(gf) * cp + sigf(gi) * tanh_f(gg);
            const float hn = sigf(go) * tanh_f(cn);
            cnew_base[row] = cn;
            if (layer == 1) out_base[row] = hn;
            hq[rl * 33 + col] = (u32)bf16_rn(hn);
        }
    }

    // ---- transpose h through LDS into packed A-frag chunks (within-wave only)
    #pragma unroll
    for (int q = 0; q < 2; ++q) {
        const int bt = bt0 + q;
        const u32* hq = hb + (wv * 2 + q) * 1056;
        #pragma unroll
        for (int h2 = 0; h2 < 2; ++h2) {
            union { u16 s[8]; uint4 v; } pk;
            #pragma unroll
            for (int e = 0; e < 8; ++e)
                pk.s[e] = (u16)hq[(lane & 31) * 33 + h2 * 16 + (lane >> 5) * 8 + e];
            *(uint4*)(hp + (size_t)(node * 2 + layer) * BH_
                      + ((size_t)bt * 64 + hhblk * 2 + h2) * 512 + lane * 8) = pk.v;
        }
    }
}

// ---------------------------------------------------------------------------
extern "C" void kernel_launch(void* const* d_in, const int* in_sizes, int n_in,
                              void* d_out, int out_size, void* d_ws, size_t ws_size,
                              hipStream_t stream)
{
    const float* input  = (const float*)d_in[0];
    const float* bridge = (const float*)d_in[1];
    const float* Wih    = (const float*)d_in[2];
    const float* Whh    = (const float*)d_in[3];
    const float* bih    = (const float*)d_in[4];
    const float* bhh    = (const float*)d_in[5];
    float* out = (float*)d_out;

    // workspace: wp 33.5MB | xp 7.9MB | hp 16.8MB | c 33.5MB | bsum
    u16* wp = (u16*)d_ws;
    u16* xp = wp + WPE;
    u16* hp = xp + XPE;
    float* c_buf = (float*)(hp + HPE);
    float* bsum  = c_buf + HPE;          // 32*BH floats for c, then bsum

    hipMemsetAsync(hp, 0, (size_t)2 * BH_ * sizeof(u16), stream);
    hipMemsetAsync(c_buf, 0, (size_t)2 * BH_ * sizeof(float), stream);

    bias_sum_k<<<32, 256, 0, stream>>>(bih, bhh, bsum);
    pack_weights<<<8192, 256, 0, stream>>>(Wih, Whh, wp);
    pack_x<<<1920, 256, 0, stream>>>(input, bridge, xp);

    // Wavefront schedule: stage T = cells (node,layer) with depth(node)+layer==T
    static const Stage stages[7] = {
        { {1},                      {0},                      {0},                      1 },
        { {1,2,5,8},                {0,1,1,1},                {1,0,0,0},                4 },
        { {2,5,8,3,6,9,12},         {1,1,1,2,5,8,8},          {1,1,1,0,0,0,0},          7 },
        { {3,6,9,12,4,7,10,13},     {2,5,8,8,3,6,9,12},       {1,1,1,1,0,0,0,0},        8 },
        { {4,7,10,13,11,14},        {3,6,9,12,10,13},         {1,1,1,1,0,0},            6 },
        { {11,14,15},               {10,13,14},               {1,1,0},                  3 },
        { {15},                     {14},                     {1},                      1 },
    };

    for (int s = 0; s < 7; ++s) {
        cell_fused<<<dim3(stages[s].cnt * 64), 128, 0, stream>>>(
            wp, xp, hp, c_buf, bsum, out, stages[s]);
    }
}

// Round 5
// 386.115 us; speedup vs baseline: 7.7316x; 1.0134x over previous
//
#include <hip/hip_runtime.h>
#include <stdint.h>

typedef unsigned short u16;
typedef uint32_t u32;
typedef short s16x8 __attribute__((ext_vector_type(8)));
typedef float fx16 __attribute__((ext_vector_type(16)));

#define B_   256
#define H_   1024
#define BH_  (B_ * H_)                  // 262144
#define WPE  ((size_t)2 * 4096 * 2048)  // W pack elems
#define WPAD 65536                      // guard for dummy pipeline stages
#define XPE  ((size_t)15 * BH_)
#define HPE  ((size_t)32 * BH_)

struct Stage { int node[8]; int par[8]; int layer[8]; int cnt; };

__device__ __forceinline__ u16 bf16_rn(float x) {
    union { float f; u32 u; } v; v.f = x;
    return (u16)((v.u + 0x7FFFu + ((v.u >> 16) & 1u)) >> 16);
}
__device__ __forceinline__ float sigf(float x) {
    return __builtin_amdgcn_rcpf(1.0f + __expf(-x));
}
__device__ __forceinline__ float tanh_f(float x) {
    return 1.0f - 2.0f * __builtin_amdgcn_rcpf(1.0f + __expf(2.0f * x));
}

// ---------------------------------------------------------------------------
// Pack W into MFMA-B fragment order, bf16. Chunk w = ((layer*4+gate)*32+cg)*128+k16;
// lane l -> W[gate*1024+cg*32+(l&31)][k16*16+(l>>5)*8+e].
// ---------------------------------------------------------------------------
__global__ __launch_bounds__(256)
void pack_weights(const float* __restrict__ Wih, const float* __restrict__ Whh,
                  u16* __restrict__ wp)
{
    const int gt = blockIdx.x * 256 + threadIdx.x;
    const int w = gt >> 6, lane = gt & 63;
    const int k16 = w & 127, cg = (w >> 7) & 31, gate = (w >> 12) & 3, layer = w >> 14;
    const int row = gate * 1024 + cg * 32 + (lane & 31);
    const int k = k16 * 16 + (lane >> 5) * 8;
    const float* src = (k < 1024)
        ? Wih + ((size_t)layer * 4096 + row) * 1024 + k
        : Whh + ((size_t)layer * 4096 + row) * 1024 + (k - 1024);
    const float4 v0 = *(const float4*)src;
    const float4 v1 = *(const float4*)(src + 4);
    const float a[8] = {v0.x, v0.y, v0.z, v0.w, v1.x, v1.y, v1.z, v1.w};
    union { u16 s[8]; uint4 v; } hi;
    #pragma unroll
    for (int e = 0; e < 8; ++e) hi.s[e] = bf16_rn(a[e]);
    *(uint4*)(wp + (size_t)w * 512 + (size_t)lane * 8) = hi.v;
}

__global__ __launch_bounds__(256)
void pack_x(const float* __restrict__ input, const float* __restrict__ bridge,
            u16* __restrict__ xp)
{
    const int gt = blockIdx.x * 256 + threadIdx.x;
    const int w = gt >> 6, lane = gt & 63;
    const int k16 = w & 63, btile = (w >> 6) & 7, n1 = w >> 9;
    const int b = btile * 32 + (lane & 31);
    const int k = k16 * 16 + (lane >> 5) * 8;
    const float* src = (k < 512)
        ? input  + ((size_t)n1 * 256 + b) * 512 + k
        : bridge + ((size_t)n1 * 256 + b) * 512 + (k - 512);
    const float4 v0 = *(const float4*)src;
    const float4 v1 = *(const float4*)(src + 4);
    const float a[8] = {v0.x, v0.y, v0.z, v0.w, v1.x, v1.y, v1.z, v1.w};
    union { u16 s[8]; uint4 v; } hi;
    #pragma unroll
    for (int e = 0; e < 8; ++e) hi.s[e] = bf16_rn(a[e]);
    *(uint4*)(xp + (size_t)w * 512 + (size_t)lane * 8) = hi.v;
}

__global__ __launch_bounds__(256)
void bias_sum_k(const float* __restrict__ bih, const float* __restrict__ bhh,
                float* __restrict__ bs)
{
    const int i = blockIdx.x * 256 + threadIdx.x;
    if (i < 8192) bs[i] = bih[i] + bhh[i];
}

// ---------------------------------------------------------------------------
// Fused cell, counted-vmcnt pipelined. Block = 512 thr (8 waves).
// Tile: 256 batch (8 btiles, 1/wave) x 32 hh x 4 gates. K=2048 in 32 steps
// of 64. Per step: stage W (16KB) + A (32KB) into 3-deep LDS ring via
// global_load_lds; raw s_barrier + vmcnt(6) (leaves next step in flight).
// blocks/cell = 32 (hhblk); grid = cnt*32; XCD = hhblk%8 stable across cells
// so per-XCD W slice (2MB/layer) stays L2-hot.
// ---------------------------------------------------------------------------
__global__ __launch_bounds__(512, 2)
void cell_fused(const u16* __restrict__ wp, const u16* __restrict__ xp,
                u16* __restrict__ hp, float* __restrict__ c_buf,
                const float* __restrict__ bsum, float* __restrict__ out,
                Stage st)
{
    __shared__ u16 Wb[3][8192];    // 3 x 16 KB: [gate(4)][k16(4)][512]
    __shared__ u16 Ab[3][16384];   // 3 x 32 KB: [btile(8)][k16(4)][512]

    const int bid = blockIdx.x;
    const int cell = bid >> 5;
    const int hhblk = bid & 31;
    const int node = st.node[cell], par = st.par[cell], layer = st.layer[cell];
    const int tid = threadIdx.x, wv = tid >> 6, lane = tid & 63;
    const int hi2 = tid >> 8;       // 0/1
    const int inner = tid & 255;    // 0..255

    // A segment bases (seg0 = K 0..1023, seg1 = K 1024..2047)
    const u16 *A0, *A1;
    if (layer == 0) {
        A0 = xp + (size_t)(node - 1) * BH_;
        A1 = hp + (size_t)(par * 2 + 0) * BH_;
    } else {
        A0 = hp + (size_t)(node * 2 + 0) * BH_;
        A1 = hp + (size_t)(par * 2 + 1) * BH_;
    }

    size_t wbase[4];
    #pragma unroll
    for (int g = 0; g < 4; ++g)
        wbase[g] = (size_t)((layer * 4 + g) * 32 + hhblk) * 65536;

    // per wave per STAGE: 2 W-loads + 4 A-loads = 6 vmcnt events
    #define STAGE(T, S) do {                                                   \
        _Pragma("unroll")                                                      \
        for (int r_ = 0; r_ < 2; ++r_) {                                       \
            const int g_ = 2 * r_ + hi2;                                       \
            __builtin_amdgcn_global_load_lds(                                  \
                (const __attribute__((address_space(1))) void*)                \
                    (wp + wbase[g_] + (size_t)(T) * 2048 + inner * 8),         \
                (__attribute__((address_space(3))) void*)                      \
                    (&Wb[S][g_ * 2048 + inner * 8]),                           \
                16, 0, 0);                                                     \
        }                                                                      \
        const u16* As_ = ((T) < 16) ? A0 : A1;                                 \
        const int t4_ = ((T) & 15) * 4;                                        \
        _Pragma("unroll")                                                      \
        for (int r_ = 0; r_ < 4; ++r_) {                                       \
            const int bt_ = 2 * r_ + hi2;                                      \
            __builtin_amdgcn_global_load_lds(                                  \
                (const __attribute__((address_space(1))) void*)                \
                    (As_ + ((size_t)bt_ * 64 + t4_) * 512 + inner * 8),        \
                (__attribute__((address_space(3))) void*)                      \
                    (&Ab[S][bt_ * 2048 + inner * 8]),                          \
                16, 0, 0);                                                     \
        }                                                                      \
    } while (0)

    #define COMPUTE(S) do {                                                    \
        _Pragma("unroll")                                                      \
        for (int kk_ = 0; kk_ < 4; ++kk_) {                                    \
            const s16x8 a_ = *(const s16x8*)                                   \
                (&Ab[S][wv * 2048 + kk_ * 512 + lane * 8]);                    \
            _Pragma("unroll")                                                  \
            for (int g_ = 0; g_ < 4; ++g_) {                                   \
                const s16x8 w_ = *(const s16x8*)                               \
                    (&Wb[S][g_ * 2048 + kk_ * 512 + lane * 8]);                \
                acc[g_] = __builtin_amdgcn_mfma_f32_32x32x16_bf16(             \
                    a_, w_, acc[g_], 0, 0, 0);                                 \
            }                                                                  \
        }                                                                      \
    } while (0)

    fx16 acc[4];
    #pragma unroll
    for (int g = 0; g < 4; ++g)
        #pragma unroll
        for (int r = 0; r < 16; ++r) acc[g][r] = 0.0f;

    STAGE(0, 0);
    STAGE(1, 1);

    #pragma unroll 1
    for (int t = 0; t < 32; ++t) {
        asm volatile("s_waitcnt vmcnt(6)" ::: "memory");  // step t landed; t+1 in flight
        __builtin_amdgcn_s_barrier();                     // publish LDS to all waves
        STAGE(t + 2, (t + 2) % 3);   // t=30,31: dummy reads into guard pad (never used)
        COMPUTE(t % 3);
    }
    __syncthreads();   // drains vmcnt(0): dummy stages land before LDS reuse

    // ---- fused gates epilogue (C/D: col=lane&31, row=(r&3)+8*(r>>2)+4*(lane>>5))
    const int col  = lane & 31;
    const int colg = hhblk * 32 + col;
    float bs4[4];
    #pragma unroll
    for (int g = 0; g < 4; ++g)
        bs4[g] = bsum[layer * 4096 + g * 1024 + colg];

    const float* cpar_base = c_buf + (size_t)(par * 2 + layer) * BH_ + colg;
    float*       cnew_base = c_buf + (size_t)(node * 2 + layer) * BH_ + colg;
    float*       out_base  = out + (size_t)(node - 1) * BH_ + colg;

    u32* hq = (u32*)(&Ab[0][0]) + wv * 1088;   // per-wave 32x33 u32 scratch

    #pragma unroll
    for (int r = 0; r < 16; ++r) {
        const int rl = 4 * (lane >> 5) + (r & 3) + 8 * (r >> 2);
        const size_t row = (size_t)(wv * 32 + rl) * 1024;
        const float gi = acc[0][r] + bs4[0];
        const float gf = acc[1][r] + bs4[1];
        const float gg = acc[2][r] + bs4[2];
        const float go = acc[3][r] + bs4[3];
        const float cp = cpar_base[row];
        const float cn = sigf(gf) * cp + sigf(gi) * tanh_f(gg);
        const float hn = sigf(go) * tanh_f(cn);
        cnew_base[row] = cn;
        if (layer == 1) out_base[row] = hn;
        hq[rl * 33 + col] = (u32)bf16_rn(hn);
    }

    // ---- transpose h (wave-local) into packed A-frag chunks for next cells
    #pragma unroll
    for (int h2 = 0; h2 < 2; ++h2) {
        union { u16 s[8]; uint4 v; } pk;
        #pragma unroll
        for (int e = 0; e < 8; ++e)
            pk.s[e] = (u16)hq[(lane & 31) * 33 + h2 * 16 + (lane >> 5) * 8 + e];
        *(uint4*)(hp + (size_t)(node * 2 + layer) * BH_
                  + ((size_t)wv * 64 + hhblk * 2 + h2) * 512 + lane * 8) = pk.v;
    }
    #undef STAGE
    #undef COMPUTE
}

// ---------------------------------------------------------------------------
extern "C" void kernel_launch(void* const* d_in, const int* in_sizes, int n_in,
                              void* d_out, int out_size, void* d_ws, size_t ws_size,
                              hipStream_t stream)
{
    const float* input  = (const float*)d_in[0];
    const float* bridge = (const float*)d_in[1];
    const float* Wih    = (const float*)d_in[2];
    const float* Whh    = (const float*)d_in[3];
    const float* bih    = (const float*)d_in[4];
    const float* bhh    = (const float*)d_in[5];
    float* out = (float*)d_out;

    u16* wp = (u16*)d_ws;
    u16* xp = wp + WPE + WPAD;
    u16* hp = xp + XPE;
    float* c_buf = (float*)(hp + HPE);
    float* bsum  = c_buf + HPE;

    hipMemsetAsync(hp, 0, (size_t)2 * BH_ * sizeof(u16), stream);
    hipMemsetAsync(c_buf, 0, (size_t)2 * BH_ * sizeof(float), stream);

    bias_sum_k<<<32, 256, 0, stream>>>(bih, bhh, bsum);
    pack_weights<<<8192, 256, 0, stream>>>(Wih, Whh, wp);
    pack_x<<<1920, 256, 0, stream>>>(input, bridge, xp);

    // Wavefront schedule: stage T = cells (node,layer) with depth(node)+layer==T
    static const Stage stages[7] = {
        { {1},                      {0},                      {0},                      1 },
        { {1,2,5,8},                {0,1,1,1},                {1,0,0,0},                4 },
        { {2,5,8,3,6,9,12},         {1,1,1,2,5,8,8},          {1,1,1,0,0,0,0},          7 },
        { {3,6,9,12,4,7,10,13},     {2,5,8,8,3,6,9,12},       {1,1,1,1,0,0,0,0},        8 },
        { {4,7,10,13,11,14},        {3,6,9,12,10,13},         {1,1,1,1,0,0},            6 },
        { {11,14,15},               {10,13,14},               {1,1,0},                  3 },
        { {15},                     {14},                     {1},                      1 },
    };

    for (int s = 0; s < 7; ++s) {
        cell_fused<<<dim3(stages[s].cnt * 32), 512, 0, stream>>>(
            wp, xp, hp, c_buf, bsum, out, stages[s]);
    }
}